// Round 17
// baseline (380.951 us; speedup 1.0000x reference)
//
#include <hip/hip_runtime.h>
#include <math.h>

// ---- dims ----
static constexpr int kB = 8, kS = 512;
static constexpr int kD = 512, kI = 1024, kNH = 8, kDH = 128;
static constexpr int kL = 4, kPRED = 96, kCOUT = 7;
static constexpr int kM = kB * kS; // 4096 rows

typedef __bf16 bf16x8 __attribute__((ext_vector_type(8)));
typedef float f32x4 __attribute__((ext_vector_type(4)));

#define MFMA_BF16(a, b, c) __builtin_amdgcn_mfma_f32_16x16x32_bf16((a), (b), (c), 0, 0, 0)

typedef __attribute__((address_space(1))) const unsigned char* as1cp;
typedef __attribute__((address_space(3))) unsigned char* as3p;
__device__ __forceinline__ void gload16(const void* g, void* l) {
  __builtin_amdgcn_global_load_lds((as1cp)g, (as3p)l, 16, 0, 0);
}

__device__ __forceinline__ unsigned short f2bf(float f) {
  union { float f; unsigned u; } v; v.f = f;
  unsigned r = v.u + 0x7fffu + ((v.u >> 16) & 1u);
  return (unsigned short)(r >> 16);
}
__device__ __forceinline__ float bf2f(unsigned short h) {
  union { unsigned u; float f; } v; v.u = (unsigned)h << 16; return v.f;
}

// ================== init: embed(+stats) | up-T(gamma-folded) | dn-T | gates-T | colsum ====
// grid: [0,4096) embed; [4096,5120) upT; [5120,5632) dnT; [5632,5680) gates;
//       [5680,5936) colsum (256 blocks: 32 cols x 8 k-segments each)
__global__ __launch_bounds__(256) void init_kernel(
    const float* __restrict__ xe, const float* __restrict__ xme,
    const float* __restrict__ embW, const float* __restrict__ embb,
    const float* __restrict__ lnw_all,
    const float* __restrict__ upW, const float* __restrict__ dnW,
    const float* __restrict__ igW, const float* __restrict__ fgW,
    float* __restrict__ x, unsigned short* __restrict__ xb,
    float* __restrict__ st1, float* __restrict__ st2,
    unsigned short* __restrict__ upWT, unsigned short* __restrict__ dnWT,
    unsigned short* __restrict__ gWT, float* __restrict__ colsum) {
  __shared__ float t[64][65];
  __shared__ float f[11], a1[4], a2[4];
  __shared__ float csx[32][8];
  int id = blockIdx.x, tid = threadIdx.x;
  if (id < 4096) {
    int m = id;
    if (tid < 7) f[tid] = xe[m * 7 + tid];
    else if (tid < 11) f[tid] = xme[m * 4 + (tid - 7)];
    __syncthreads();
    float v0 = embb[tid], v1 = embb[256 + tid];
#pragma unroll
    for (int e = 0; e < 11; ++e) {
      v0 += f[e] * embW[e * kD + tid];
      v1 += f[e] * embW[e * kD + 256 + tid];
    }
    x[(size_t)m * kD + tid] = v0;
    x[(size_t)m * kD + 256 + tid] = v1;
    xb[(size_t)m * kD + tid] = f2bf(v0);
    xb[(size_t)m * kD + 256 + tid] = f2bf(v1);
    float s1 = v0 + v1, s2 = v0 * v0 + v1 * v1;
#pragma unroll
    for (int o = 1; o < 64; o <<= 1) { s1 += __shfl_xor(s1, o, 64); s2 += __shfl_xor(s2, o, 64); }
    if ((tid & 63) == 0) { a1[tid >> 6] = s1; a2[tid >> 6] = s2; }
    __syncthreads();
    if (tid == 0) {
      st1[m] = a1[0] + a1[1] + a1[2] + a1[3];
      st2[m] = a2[0] + a2[1] + a2[2] + a2[3];
    } else if (tid < 4) {
      st1[tid * 4096 + m] = 0.f;
      st2[tid * 4096 + m] = 0.f;
    }
  } else if (id < 5120) {
    int tt = id - 4096;
    int l = tt >> 8, rem = tt & 255;
    int n0 = (rem >> 3) * 64, k0 = (rem & 7) * 64;
    const float* Wl = upW + (size_t)l * 2048 * 512;
    const float* lnw = lnw_all + (size_t)l * kD;
    unsigned short* WTl = upWT + (size_t)l * 2048 * 512;
    for (int idx = tid; idx < 4096; idx += 256) {
      int r = idx >> 6, c = idx & 63;
      t[r][c] = Wl[(size_t)(k0 + r) * 2048 + n0 + c];
    }
    __syncthreads();
    for (int idx = tid; idx < 4096; idx += 256) {
      int r = idx >> 6, c = idx & 63;
      WTl[(size_t)(n0 + r) * 512 + k0 + c] = f2bf(lnw[k0 + c] * t[c][r]);
    }
  } else if (id < 5632) {
    int tt = id - 5120;
    int l = tt >> 7, rem = tt & 127;
    int n0 = (rem >> 4) * 64, k0 = (rem & 15) * 64;
    const float* Wl = dnW + (size_t)l * 512 * 1024;
    unsigned short* WTl = dnWT + (size_t)l * 512 * 1024;
    for (int idx = tid; idx < 4096; idx += 256) {
      int r = idx >> 6, c = idx & 63;
      t[r][c] = Wl[(size_t)(k0 + r) * 512 + n0 + c];
    }
    __syncthreads();
    for (int idx = tid; idx < 4096; idx += 256) {
      int r = idx >> 6, c = idx & 63;
      WTl[(size_t)(n0 + r) * 1024 + k0 + c] = f2bf(t[c][r]);
    }
  } else if (id < 5680) {
    int tt = id - 5632;
    int l = tt / 12, kc = tt % 12;
    int k = kc * 256 + tid;
    const float* igl = igW + (size_t)l * 3072 * 8;
    const float* fgl = fgW + (size_t)l * 3072 * 8;
    unsigned short* gl = gWT + (size_t)l * 16 * 3072;
#pragma unroll
    for (int h = 0; h < 8; ++h) {
      gl[(size_t)h * 3072 + k] = f2bf(igl[(size_t)k * 8 + h]);
      gl[(size_t)(8 + h) * 3072 + k] = f2bf(fgl[(size_t)k * 8 + h]);
    }
  } else {
    // colsum: 256 blocks; block handles 32 cols x 8 k-segments (64 k each)
    int tt = id - 5680;
    int l = tt >> 6, n0 = (tt & 63) * 32;
    int c = tid >> 3, seg = tid & 7;
    int col = n0 + c;
    const float* Wl = upW + (size_t)l * 2048 * 512;
    const float* lnw = lnw_all + (size_t)l * kD;
    float ps = 0.f;
#pragma unroll 4
    for (int j = 0; j < 64; ++j) {
      int k = seg * 64 + j;
      ps += bf2f(f2bf(lnw[k] * Wl[(size_t)k * 2048 + col]));
    }
    csx[c][seg] = ps;
    __syncthreads();
    if (seg == 0) {
      float cs = 0.f;
#pragma unroll
      for (int j = 0; j < 8; ++j) cs += csx[c][j];
      colsum[(size_t)l * 2048 + col] = cs;
    }
  }
}

// ============== up-GEMM: U = LNfactored(X) @ upWT'^T + bias  (BM=128, NBN=16) =============
__global__ __launch_bounds__(256) void gemm_up_kernel(
    const unsigned short* __restrict__ A, const unsigned short* __restrict__ BT,
    const float* __restrict__ bias, const float* __restrict__ colsum,
    const float* __restrict__ st1, const float* __restrict__ st2,
    unsigned short* __restrict__ C, int nwg) {
  constexpr int BM = 128, NBN = 16, Kd = 512, N = 2048;
  constexpr int A_ISS = BM / 8, PER_W = (A_ISS + 16) / 4, MR = BM / 32;
  __shared__ __align__(16) char As[BM * 128];
  __shared__ __align__(16) char Bs[16384];
  int tid = threadIdx.x, w = tid >> 6, l = tid & 63;
  int lr = l & 15, lg = l >> 4;
  int id = blockIdx.x;
  int q = nwg >> 3, r = nwg & 7;
  int xcd = id & 7, pos = id >> 3;
  int wg = (xcd < r ? xcd * (q + 1) : r * (q + 1) + (xcd - r) * q) + pos;
  int bn = wg % NBN, bm = wg / NBN;
  int wrow = (w >> 1) * (BM / 2), wcol = (w & 1) * 64;
  f32x4 acc[MR][4] = {};
  for (int kt = 0; kt < Kd; kt += 64) {
    __syncthreads();
#pragma unroll
    for (int j = 0; j < PER_W; ++j) {
      int g = w * PER_W + j;
      bool isA = g < A_ISS;
      int ii = isA ? g : g - A_ISS;
      int row = ii * 8 + (l >> 3);
      int chunk = (l & 7) ^ (row & 7);
      const unsigned short* src = isA
          ? A + ((size_t)(bm * BM + row) * Kd + kt) + chunk * 8
          : BT + ((size_t)(bn * 128 + row) * Kd + kt) + chunk * 8;
      char* dst = (isA ? As : Bs) + ii * 1024;
      gload16(src, dst);
    }
    __syncthreads();
#pragma unroll
    for (int kk = 0; kk < 2; ++kk) {
      bf16x8 af[MR], bfr[4];
#pragma unroll
      for (int m = 0; m < MR; ++m) {
        int row = wrow + m * 16 + lr;
        int ch = (kk * 4 + lg) ^ (row & 7);
        af[m] = *(const bf16x8*)(As + row * 128 + ch * 16);
      }
#pragma unroll
      for (int n = 0; n < 4; ++n) {
        int row = wcol + n * 16 + lr;
        int ch = (kk * 4 + lg) ^ (row & 7);
        bfr[n] = *(const bf16x8*)(Bs + row * 128 + ch * 16);
      }
#pragma unroll
      for (int m = 0; m < MR; ++m)
#pragma unroll
        for (int n = 0; n < 4; ++n)
          acc[m][n] = MFMA_BF16(af[m], bfr[n], acc[m][n]);
    }
  }
  float mu_r[MR][4], rs_r[MR][4];
#pragma unroll
  for (int m = 0; m < MR; ++m)
#pragma unroll
    for (int i = 0; i < 4; ++i) {
      int row = bm * BM + wrow + m * 16 + lg * 4 + i;
      float s1 = st1[row] + st1[4096 + row] + st1[8192 + row] + st1[12288 + row];
      float s2 = st2[row] + st2[4096 + row] + st2[8192 + row] + st2[12288 + row];
      float mu = s1 * (1.f / 512.f);
      float var = s2 * (1.f / 512.f) - mu * mu;
      mu_r[m][i] = mu;
      rs_r[m][i] = rsqrtf(var + 1e-5f);
    }
#pragma unroll
  for (int n = 0; n < 4; ++n) {
    int col = bn * 128 + wcol + n * 16 + lr;
    float bv = bias[col];
    float cs = colsum[col];
#pragma unroll
    for (int m = 0; m < MR; ++m)
#pragma unroll
      for (int i = 0; i < 4; ++i) {
        int row = bm * BM + wrow + m * 16 + lg * 4 + i;
        float v = rs_r[m][i] * (acc[m][n][i] - mu_r[m][i] * cs) + bv;
        C[(size_t)row * N + col] = f2bf(v);
      }
  }
}

// ============== dn-GEMM: X += HHb @ dnWT^T + bias; emits Xb bf16 + row-stats partials ======
__global__ __launch_bounds__(256) void gemm_dn_kernel(
    const unsigned short* __restrict__ A, const unsigned short* __restrict__ BT,
    const float* __restrict__ bias, float* __restrict__ X,
    unsigned short* __restrict__ Xb, float* __restrict__ st1, float* __restrict__ st2,
    int nwg) {
  constexpr int BM = 64, NBN = 4, Kd = 1024, N = 512;
  constexpr int A_ISS = BM / 8, PER_W = (A_ISS + 16) / 4, MR = BM / 32;
  __shared__ __align__(16) char As[BM * 128];
  __shared__ __align__(16) char Bs[16384];
  __shared__ float sst[4][32][2];
  int tid = threadIdx.x, w = tid >> 6, l = tid & 63;
  int lr = l & 15, lg = l >> 4;
  int id = blockIdx.x;
  int q = nwg >> 3, r = nwg & 7;
  int xcd = id & 7, pos = id >> 3;
  int wg = (xcd < r ? xcd * (q + 1) : r * (q + 1) + (xcd - r) * q) + pos;
  int bn = wg % NBN, bm = wg / NBN;
  int wrow = (w >> 1) * (BM / 2), wcol = (w & 1) * 64;
  f32x4 acc[MR][4] = {};
  for (int kt = 0; kt < Kd; kt += 64) {
    __syncthreads();
#pragma unroll
    for (int j = 0; j < PER_W; ++j) {
      int g = w * PER_W + j;
      bool isA = g < A_ISS;
      int ii = isA ? g : g - A_ISS;
      int row = ii * 8 + (l >> 3);
      int chunk = (l & 7) ^ (row & 7);
      const unsigned short* src = isA
          ? A + ((size_t)(bm * BM + row) * Kd + kt) + chunk * 8
          : BT + ((size_t)(bn * 128 + row) * Kd + kt) + chunk * 8;
      char* dst = (isA ? As : Bs) + ii * 1024;
      gload16(src, dst);
    }
    __syncthreads();
#pragma unroll
    for (int kk = 0; kk < 2; ++kk) {
      bf16x8 af[MR], bfr[4];
#pragma unroll
      for (int m = 0; m < MR; ++m) {
        int row = wrow + m * 16 + lr;
        int ch = (kk * 4 + lg) ^ (row & 7);
        af[m] = *(const bf16x8*)(As + row * 128 + ch * 16);
      }
#pragma unroll
      for (int n = 0; n < 4; ++n) {
        int row = wcol + n * 16 + lr;
        int ch = (kk * 4 + lg) ^ (row & 7);
        bfr[n] = *(const bf16x8*)(Bs + row * 128 + ch * 16);
      }
#pragma unroll
      for (int m = 0; m < MR; ++m)
#pragma unroll
        for (int n = 0; n < 4; ++n)
          acc[m][n] = MFMA_BF16(af[m], bfr[n], acc[m][n]);
    }
  }
  float ps1[MR][4] = {}, ps2[MR][4] = {};
#pragma unroll
  for (int n = 0; n < 4; ++n) {
    int col = bn * 128 + wcol + n * 16 + lr;
    float bv = bias[col];
#pragma unroll
    for (int m = 0; m < MR; ++m)
#pragma unroll
      for (int i = 0; i < 4; ++i) {
        int row = bm * BM + wrow + m * 16 + lg * 4 + i;
        float v = acc[m][n][i] + bv + X[(size_t)row * N + col];
        X[(size_t)row * N + col] = v;
        Xb[(size_t)row * N + col] = f2bf(v);
        ps1[m][i] += v;
        ps2[m][i] += v * v;
      }
  }
#pragma unroll
  for (int m = 0; m < MR; ++m)
#pragma unroll
    for (int i = 0; i < 4; ++i) {
#pragma unroll
      for (int off = 1; off < 16; off <<= 1) {
        ps1[m][i] += __shfl_xor(ps1[m][i], off, 16);
        ps2[m][i] += __shfl_xor(ps2[m][i], off, 16);
      }
    }
  if (lr == 0) {
#pragma unroll
    for (int m = 0; m < MR; ++m)
#pragma unroll
      for (int i = 0; i < 4; ++i) {
        int lrow = m * 16 + lg * 4 + i;  // 0..31 within wave's row set
        sst[w][lrow][0] = ps1[m][i];
        sst[w][lrow][1] = ps2[m][i];
      }
  }
  __syncthreads();
  if (tid < 64) {
    int lrow = tid & 31, half = tid >> 5;
    int wA = half * 2, wB = half * 2 + 1;
    float s1 = sst[wA][lrow][0] + sst[wB][lrow][0];
    float s2 = sst[wA][lrow][1] + sst[wB][lrow][1];
    int grow = bm * BM + half * 32 + lrow;
    st1[(size_t)bn * 4096 + grow] = s1;
    st2[(size_t)bn * 4096 + grow] = s2;
  }
}

// ==== fused causal conv(K=4)+silu + headwise q,k,v (+ direct V^T write); 4 s per block ====
__global__ __launch_bounds__(256) void convhead_kernel(
    const unsigned short* __restrict__ u, const float* __restrict__ cw,
    const float* __restrict__ cb,
    const float* __restrict__ Wq, const float* __restrict__ Wk, const float* __restrict__ Wv,
    unsigned short* __restrict__ xcb, unsigned short* __restrict__ qb,
    unsigned short* __restrict__ kb, unsigned short* __restrict__ vb,
    unsigned short* __restrict__ vt) {
  int id = blockIdx.x;
  int unit = (id & 7) * 128 + (id >> 3);  // bijective for 1024 blocks
  int b = unit >> 7, sq = (unit & 127) * 4;
  int n = threadIdx.x;  // channels n*4 .. n*4+3
  float xm[7][4];
#pragma unroll
  for (int j = 0; j < 7; ++j) {
    int sp = sq - 3 + j;
    if (sp >= 0) {
      unsigned long long raw = *(const unsigned long long*)&u[((size_t)(b * kS + sp)) * (2 * kI) + n * 4];
#pragma unroll
      for (int i = 0; i < 4; ++i) xm[j][i] = bf2f((unsigned short)(raw >> (i * 16)));
    } else {
#pragma unroll
      for (int i = 0; i < 4; ++i) xm[j][i] = 0.f;
    }
  }
  float4 cb4 = *(const float4*)&cb[n * 4];
  const float* cbp = &cb4.x;
  float cwv[4][4];
#pragma unroll
  for (int i = 0; i < 4; ++i) *(float4*)cwv[i] = *(const float4*)&cw[(n * 4 + i) * 4];
  float wqv[16], wkv[16], wvv[16];
#pragma unroll
  for (int o2 = 0; o2 < 4; ++o2) {
    *(float4*)&wqv[o2 * 4] = *(const float4*)&Wq[n * 16 + o2 * 4];
    *(float4*)&wkv[o2 * 4] = *(const float4*)&Wk[n * 16 + o2 * 4];
    *(float4*)&wvv[o2 * 4] = *(const float4*)&Wv[n * 16 + o2 * 4];
  }
  unsigned long long vtv[4] = {0, 0, 0, 0};  // per output channel o: 4 s-values packed
#pragma unroll
  for (int t = 0; t < 4; ++t) {
    int s = sq + t;
    float xc[4];
    unsigned long long xcv = 0;
#pragma unroll
    for (int i = 0; i < 4; ++i) {
      float acc = cbp[i] + xm[t][i] * cwv[i][0] + xm[t + 1][i] * cwv[i][1] +
                  xm[t + 2][i] * cwv[i][2] + xm[t + 3][i] * cwv[i][3];
      xc[i] = acc / (1.f + __expf(-acc));
      xcv |= (unsigned long long)f2bf(xc[i]) << (i * 16);
    }
    *(unsigned long long*)&xcb[((size_t)(b * kS + s)) * kI + n * 4] = xcv;
    unsigned long long qv = 0, kv = 0, vv = 0;
#pragma unroll
    for (int o = 0; o < 4; ++o) {
      float aq = 0, ak = 0, av = 0;
#pragma unroll
      for (int i = 0; i < 4; ++i) {
        aq += xc[i] * wqv[o * 4 + i];
        ak += xc[i] * wkv[o * 4 + i];
        av += xm[t + 3][i] * wvv[o * 4 + i];
      }
      unsigned short avb = f2bf(av);
      qv |= (unsigned long long)f2bf(aq) << (o * 16);
      kv |= (unsigned long long)f2bf(ak) << (o * 16);
      vv |= (unsigned long long)avb << (o * 16);
      vtv[o] |= (unsigned long long)avb << (t * 16);
    }
    size_t base = ((size_t)(b * 8 + (n >> 5)) * kS + s) * kDH + (n & 31) * 4;
    *(unsigned long long*)&qb[base] = qv;
    *(unsigned long long*)&kb[base] = kv;
    *(unsigned long long*)&vb[base] = vv;
  }
  // direct V^T write: vt[bh][d][sq..sq+3], one 8B store per output channel
  {
    int bh = b * 8 + (n >> 5);
    int d0 = (n & 31) * 4;
#pragma unroll
    for (int o = 0; o < 4; ++o) {
      size_t vbase = ((size_t)bh * kDH + d0 + o) * kS + sq;
      *(unsigned long long*)&vt[vbase] = vtv[o];
    }
  }
}

// ============ prep: gates MFMA only (192 blocks) ====
__global__ __launch_bounds__(256) void prep_kernel(
    const unsigned short* __restrict__ qb, const unsigned short* __restrict__ kb,
    const unsigned short* __restrict__ vb, const unsigned short* __restrict__ gWT,
    float* __restrict__ IGp, float* __restrict__ FGp) {
  __shared__ __align__(16) char smem[16640];
  int id = blockIdx.x;
  int tid = threadIdx.x;
  int src = id >> 6;
  int blk = id & 63;
  int b = blk >> 3, s0 = (blk & 7) * 64;
  int w = tid >> 6, l = tid & 63;
  int lr = l & 15, lg = l >> 4;
  char* Ts = smem;
  const unsigned short* srcb = (src == 0) ? qb : (src == 1) ? kb : vb;
  f32x4 acc = {};
  for (int kc8 = 0; kc8 < 8; ++kc8) {
    const unsigned short* srcbase = srcb + ((size_t)(b * 8 + kc8) * kS + s0) * kDH;
    __syncthreads();
#pragma unroll
    for (int j = 0; j < 4; ++j) {
      int issue = w * 4 + j;
      int row = issue * 4 + (l >> 4);
      int chunk = (l & 15) ^ (row & 7);
      gload16(srcbase + row * 128 + chunk * 8, Ts + issue * 1024);
    }
    __syncthreads();
#pragma unroll
    for (int kk = 0; kk < 4; ++kk) {
      int arow = w * 16 + lr;
      int ch = (kk * 4 + lg) ^ (arow & 7);
      bf16x8 af = *(const bf16x8*)(Ts + arow * 256 + ch * 16);
      bf16x8 bfv = *(const bf16x8*)(gWT + (size_t)lr * 3072 + (src * 8 + kc8) * 128 + kk * 32 + lg * 8);
      acc = MFMA_BF16(af, bfv, acc);
    }
  }
  float* IGo = IGp + (size_t)src * 64 * kS;
  float* FGo = FGp + (size_t)src * 64 * kS;
#pragma unroll
  for (int i = 0; i < 4; ++i) {
    int s = s0 + w * 16 + lg * 4 + i;
    if (lr < 8) IGo[((size_t)(b * 8) + lr) * kS + s] = acc[i];
    else FGo[((size_t)(b * 8) + lr - 8) * kS + s] = acc[i];
  }
}

// ======================= mLSTM parallel via MFMA, fused scan + mh_norm/skip/gate ==========
__global__ __launch_bounds__(512) void mlstm_mfma_kernel(
    const unsigned short* __restrict__ qb, const unsigned short* __restrict__ kb,
    const unsigned short* __restrict__ vt,
    const float* __restrict__ IGp, const float* __restrict__ FGp,
    const float* __restrict__ igb, const float* __restrict__ fgb,
    const unsigned short* __restrict__ u, const unsigned short* __restrict__ xcb,
    const float* __restrict__ onw, const float* __restrict__ skw,
    unsigned short* __restrict__ hhb) {
  int id = blockIdx.x;
  int bh = (id & 7) * 8 + ((id >> 3) & 7);  // each XCD sees only 8 heads
  int pr = id >> 6;                          // 0..3
  int rtA = 7 - pr, rtB = pr;
  int b = bh >> 3, nh = bh & 7;
  int tid = threadIdx.x, w = tid >> 6, l = tid & 63;
  int g = w >> 2, wl = w & 3;
  int rt = (g == 0) ? rtA : rtB;
  int lr = l & 15, lg = l >> 4;
  __shared__ __align__(16) char Ks[2][16384];  // [64 s][128 d] bf16, RB=256
  __shared__ __align__(16) char Vs[2][16384];  // [128 d][64 s] bf16, RB=128
  __shared__ __align__(16) char Ps[8][2048];   // per-wave [16][64] bf16, RB=128
  __shared__ float avs[512], incs[512], pms[512];
  __shared__ float wsum[8], wmax[8];

  const unsigned short* kbh = kb + (size_t)bh * kS * kDH;
  const unsigned short* vbh = vt + (size_t)bh * kDH * kS;

  // prologue: stage tile 0 into buffer 0 (all 8 waves: 2 K-issues + 2 V-issues each)
#pragma unroll
  for (int j = 0; j < 2; ++j) {
    int issue = w * 2 + j;
    int row = issue * 4 + (l >> 4);
    int chunk = (l & 15) ^ (row & 7);
    gload16(kbh + row * 128 + chunk * 8, Ks[0] + issue * 1024);
  }
#pragma unroll
  for (int j = 0; j < 2; ++j) {
    int vi = w * 2 + j;
    int row = vi * 8 + (l >> 3);
    int chunk = (l & 7) ^ (row & 7);
    gload16(vbh + (size_t)row * kS + chunk * 8, Vs[0] + vi * 1024);
  }

  // ---- in-block scan for this head (hidden under tile-0 DMA) ----
  {
    int lane = tid & 63, wid2 = tid >> 6;
    const size_t ss = (size_t)64 * kS;
    size_t o = (size_t)bh * kS + tid;
    float igv = IGp[o] + IGp[ss + o] + IGp[2 * ss + o] + igb[nh];
    float fgv = FGp[o] + FGp[ss + o] + FGp[2 * ss + o] + fgb[nh];
    float lf = fminf(fgv, 0.f) - log1pf(__expf(-fabsf(fgv)));
    float x = lf;
#pragma unroll
    for (int off = 1; off < 64; off <<= 1) {
      float v = __shfl_up(x, off, 64);
      if (lane >= off) x += v;
    }
    if (lane == 63) wsum[wid2] = x;
    __syncthreads();
    float base = 0.f;
    for (int i2 = 0; i2 < wid2; ++i2) base += wsum[i2];
    float inct = x + base;
    incs[tid] = inct;
    float av = igv - inct;
    avs[tid] = 0.08838834764831845f * __expf(av);
    float y = av;
#pragma unroll
    for (int off = 1; off < 64; off <<= 1) {
      float v = __shfl_up(y, off, 64);
      if (lane >= off) y = fmaxf(y, v);
    }
    if (lane == 63) wmax[wid2] = y;
    __syncthreads();
    float mb2 = y;
    for (int i2 = 0; i2 < wid2; ++i2) mb2 = fmaxf(mb2, wmax[i2]);
    pms[tid] = mb2;
  }

  bf16x8 qf[4];
  int qrow = rt * 64 + wl * 16 + lr;
  const unsigned short* qrp = qb + ((size_t)bh * kS + qrow) * kDH + lg * 8;
#pragma unroll
  for (int kk = 0; kk < 4; ++kk) qf[kk] = *(const bf16x8*)(qrp + kk * 32);

  __syncthreads();  // scan results + tile-0 staging visible

  float pm_r[4], epm[4];
#pragma unroll
  for (int i = 0; i < 4; ++i) {
    pm_r[i] = pms[rt * 64 + wl * 16 + lg * 4 + i];
    epm[i] = __expf(-pm_r[i]);
  }

  f32x4 oacc[8] = {};
  float rsum[4] = {};

  int cur = 0;
#pragma unroll 1
  for (int ct = 0; ct <= rtA; ++ct) {
    if (ct < rtA) {
      const unsigned short* kbase = kbh + (size_t)(ct + 1) * 64 * kDH;
      const unsigned short* vbase = vbh + (size_t)(ct + 1) * 64;
#pragma unroll
      for (int j = 0; j < 2; ++j) {
        int issue = w * 2 + j;
        int row = issue * 4 + (l >> 4);
        int chunk = (l & 15) ^ (row & 7);
        gload16(kbase + row * 128 + chunk * 8, Ks[cur ^ 1] + issue * 1024);
      }
#pragma unroll
      for (int j = 0; j < 2; ++j) {
        int vi = w * 2 + j;
        int row = vi * 8 + (l >> 3);
        int chunk = (l & 7) ^ (row & 7);
        gload16(vbase + (size_t)row * kS + chunk * 8, Vs[cur ^ 1] + vi * 1024);
      }
    }
    if (ct <= rt) {
      // QK^T
      f32x4 sacc[4] = {};
      __builtin_amdgcn_s_setprio(1);
#pragma unroll
      for (int n = 0; n < 4; ++n) {
#pragma unroll
        for (int kk = 0; kk < 4; ++kk) {
          int krow = n * 16 + lr;
          int ch = (kk * 4 + lg) ^ (krow & 7);
          bf16x8 kf = *(const bf16x8*)(Ks[cur] + krow * 256 + ch * 16);
          sacc[n] = MFMA_BF16(qf[kk], kf, sacc[n]);
        }
      }
      __builtin_amdgcn_s_setprio(0);
      // transform scores -> P (bf16 in per-wave LDS), accumulate row sums.
      // Mask peel: cndmask chain only on the diagonal tile (ct == rt).
      if (ct < rt) {
#pragma unroll
        for (int n = 0; n < 4; ++n) {
          float eav = avs[ct * 64 + n * 16 + lr];
#pragma unroll
          for (int i = 0; i < 4; ++i) {
            float s = sacc[n][i] * (eav * epm[i]);
            rsum[i] += s;
            int prow = lg * 4 + i, pcol = n * 16 + lr;
            int byte = prow * 128 + ((((pcol >> 3) ^ (prow & 7))) << 4) + (pcol & 7) * 2;
            *(unsigned short*)(Ps[w] + byte) = f2bf(s);
          }
        }
      } else {
#pragma unroll
        for (int n = 0; n < 4; ++n) {
          float eav = avs[ct * 64 + n * 16 + lr];
          int cg = ct * 64 + n * 16 + lr;
#pragma unroll
          for (int i = 0; i < 4; ++i) {
            int rg = rt * 64 + wl * 16 + lg * 4 + i;
            float s = (cg <= rg) ? sacc[n][i] * (eav * epm[i]) : 0.f;
            rsum[i] += s;
            int prow = lg * 4 + i, pcol = n * 16 + lr;
            int byte = prow * 128 + ((((pcol >> 3) ^ (prow & 7))) << 4) + (pcol & 7) * 2;
            *(unsigned short*)(Ps[w] + byte) = f2bf(s);
          }
        }
      }
      // PV
      __builtin_amdgcn_s_setprio(1);
#pragma unroll
      for (int kk = 0; kk < 2; ++kk) {
        int prow = lr;
        int pch = (kk * 4 + lg) ^ (prow & 7);
        bf16x8 pf = *(const bf16x8*)(Ps[w] + prow * 128 + pch * 16);
#pragma unroll
        for (int nb = 0; nb < 8; ++nb) {
          int vrow = nb * 16 + lr;
          int vch = (kk * 4 + lg) ^ (vrow & 7);
          bf16x8 vf = *(const bf16x8*)(Vs[cur] + vrow * 128 + vch * 16);
          oacc[nb] = MFMA_BF16(pf, vf, oacc[nb]);
        }
      }
      __builtin_amdgcn_s_setprio(0);
    }
    __syncthreads();  // drains staging DMA + protects buffer swap
    cur ^= 1;
  }

#pragma unroll
  for (int i = 0; i < 4; ++i)
#pragma unroll
    for (int off = 1; off < 16; off <<= 1) rsum[i] += __shfl_xor(rsum[i], off, 16);
  float ninv[4];
#pragma unroll
  for (int i = 0; i < 4; ++i) {
    int rg = rt * 64 + wl * 16 + lg * 4 + i;
    float e0 = __expf(-incs[rg] - pm_r[i]);
    float nn = fmaxf(fabsf(rsum[i]), e0);
    ninv[i] = 1.f / (nn + 1e-6f);
  }
  // ---- fused mh_norm (LN over DH=128 within 16-lane groups) + skip + output gate ----
  float val[8][4];
  float s1[4] = {}, s2[4] = {};
#pragma unroll
  for (int nb = 0; nb < 8; ++nb)
#pragma unroll
    for (int i = 0; i < 4; ++i) {
      float v = oacc[nb][i] * ninv[i];
      val[nb][i] = v;
      s1[i] += v; s2[i] += v * v;
    }
#pragma unroll
  for (int i = 0; i < 4; ++i) {
#pragma unroll
    for (int off = 1; off < 16; off <<= 1) {
      s1[i] += __shfl_xor(s1[i], off, 16);
      s2[i] += __shfl_xor(s2[i], off, 16);
    }
  }
#pragma unroll
  for (int i = 0; i < 4; ++i) {
    int rg = rt * 64 + wl * 16 + lg * 4 + i;
    float mu = s1[i] * (1.f / 128.f);
    float var = s2[i] * (1.f / 128.f) - mu * mu;
    float rstd = rsqrtf(var + 1e-5f);
    size_t rowbase = (size_t)(b * kS + rg);
    const unsigned short* uz = u + rowbase * (2 * kI) + kI + nh * kDH;
    const unsigned short* xz = xcb + rowbase * kI + nh * kDH;
    unsigned short* hz = hhb + rowbase * kI + nh * kDH;
#pragma unroll
    for (int nb = 0; nb < 8; ++nb) {
      int c = nh * kDH + nb * 16 + lr;
      int cc = nb * 16 + lr;
      float nv = (val[nb][i] - mu) * rstd * onw[c];
      float z = bf2f(uz[cc]);
      float sz = z / (1.f + __expf(-z));
      float xcv = bf2f(xz[cc]);
      hz[cc] = f2bf((nv + skw[c] * xcv) * sz);
    }
  }
}

// ======================= post-norm + head projection (last 96 rows/batch) =======================
__global__ __launch_bounds__(256) void head_kernel(
    const float* __restrict__ x, const float* __restrict__ pw,
    const float* __restrict__ hW, const float* __restrict__ hb, float* __restrict__ out) {
  int row = blockIdx.x;  // 0..767
  int b = row / kPRED, p = row % kPRED;
  int m = b * kS + (kS - kPRED) + p;
  int tid = threadIdx.x;
  float v0 = x[(size_t)m * kD + tid];
  float v1 = x[(size_t)m * kD + 256 + tid];
  float s1 = v0 + v1, s2 = v0 * v0 + v1 * v1;
#pragma unroll
  for (int o = 1; o < 64; o <<= 1) { s1 += __shfl_xor(s1, o, 64); s2 += __shfl_xor(s2, o, 64); }
  __shared__ float a1[4], a2[4];
  if ((tid & 63) == 0) { a1[tid >> 6] = s1; a2[tid >> 6] = s2; }
  __syncthreads();
  float t1 = a1[0] + a1[1] + a1[2] + a1[3];
  float t2 = a2[0] + a2[1] + a2[2] + a2[3];
  float mu = t1 * (1.f / kD);
  float var = t2 * (1.f / kD) - mu * mu;
  float rs = rsqrtf(var + 1e-5f);
  __shared__ float buf[512];
  buf[tid] = (v0 - mu) * rs * pw[tid];
  buf[256 + tid] = (v1 - mu) * rs * pw[256 + tid];
  __syncthreads();
  float acc[7] = {};
  for (int kk = tid; kk < 512; kk += 256) {
    float g = buf[kk];
#pragma unroll
    for (int n = 0; n < 7; ++n) acc[n] += g * hW[kk * 7 + n];
  }
  __shared__ float red[256 * 9];
#pragma unroll
  for (int n = 0; n < 7; ++n) red[tid * 9 + n] = acc[n];
  __syncthreads();
  for (int off = 128; off >= 1; off >>= 1) {
    if (tid < off) {
#pragma unroll
      for (int n = 0; n < 7; ++n) red[tid * 9 + n] += red[(tid + off) * 9 + n];
    }
    __syncthreads();
  }
  if (tid < 7) out[(size_t)row * 7 + tid] = red[tid] + hb[tid];
}

// ======================= host launch =======================
extern "C" void kernel_launch(void* const* d_in, const int* in_sizes, int n_in,
                              void* d_out, int out_size, void* d_ws, size_t ws_size,
                              hipStream_t stream) {
  const float* x_enc    = (const float*)d_in[0];
  const float* x_mark   = (const float*)d_in[1];
  const float* emb_W    = (const float*)d_in[4];
  const float* emb_b    = (const float*)d_in[5];
  const float* blk_ln_w = (const float*)d_in[6];
  const float* up_W     = (const float*)d_in[7];
  const float* up_b     = (const float*)d_in[8];
  const float* conv_w   = (const float*)d_in[9];
  const float* conv_b   = (const float*)d_in[10];
  const float* Wq       = (const float*)d_in[11];
  const float* Wk       = (const float*)d_in[12];
  const float* Wv       = (const float*)d_in[13];
  const float* ig_W     = (const float*)d_in[14];
  const float* ig_b     = (const float*)d_in[15];
  const float* fg_W     = (const float*)d_in[16];
  const float* fg_b     = (const float*)d_in[17];
  const float* onorm_w  = (const float*)d_in[18];
  const float* skip_w   = (const float*)d_in[19];
  const float* down_W   = (const float*)d_in[20];
  const float* down_b   = (const float*)d_in[21];
  const float* post_w   = (const float*)d_in[22];
  const float* head_W   = (const float*)d_in[23];
  const float* head_b   = (const float*)d_in[24];
  float* out = (float*)d_out;

  char* ws = (char*)d_ws;
  float* X  = (float*)ws;                     ws += (size_t)kM * kD * 4;
  unsigned short* Xb   = (unsigned short*)ws; ws += (size_t)kM * kD * 2;
  unsigned short* U    = (unsigned short*)ws; ws += (size_t)kM * 2 * kI * 2;
  unsigned short* XCb  = (unsigned short*)ws; ws += (size_t)kM * kI * 2;
  unsigned short* HHb  = (unsigned short*)ws; ws += (size_t)kM * kI * 2;
  unsigned short* qb   = (unsigned short*)ws; ws += (size_t)kM * kI * 2;
  unsigned short* kbuf = (unsigned short*)ws; ws += (size_t)kM * kI * 2;
  unsigned short* vb   = (unsigned short*)ws; ws += (size_t)kM * kI * 2;
  unsigned short* vt   = (unsigned short*)ws; ws += (size_t)kM * kI * 2;
  unsigned short* upWT = (unsigned short*)ws; ws += (size_t)kL * 2 * kI * kD * 2;
  unsigned short* dnWT = (unsigned short*)ws; ws += (size_t)kL * kD * kI * 2;
  unsigned short* gWT  = (unsigned short*)ws; ws += (size_t)kL * 16 * 3072 * 2;
  float* IGp = (float*)ws; ws += (size_t)3 * 64 * kS * 4;
  float* FGp = (float*)ws; ws += (size_t)3 * 64 * kS * 4;
  float* ST1 = (float*)ws; ws += (size_t)4 * kM * 4;
  float* ST2 = (float*)ws; ws += (size_t)4 * kM * 4;
  float* CSUM = (float*)ws; ws += (size_t)kL * 2 * kI * 4;

  init_kernel<<<5936, 256, 0, stream>>>(
      x_enc, x_mark, emb_W, emb_b, blk_ln_w, up_W, down_W, ig_W, fg_W,
      X, Xb, ST1, ST2, upWT, dnWT, gWT, CSUM);

  for (int l = 0; l < kL; ++l) {
    const float* upbl = up_b + (size_t)l * 2 * kI;
    const float* cwl  = conv_w + (size_t)l * kI * 4;
    const float* cbl  = conv_b + (size_t)l * kI;
    const float* wql  = Wq + (size_t)l * 256 * 16;
    const float* wkl  = Wk + (size_t)l * 256 * 16;
    const float* wvl  = Wv + (size_t)l * 256 * 16;
    const float* igbl = ig_b + (size_t)l * kNH;
    const float* fgbl = fg_b + (size_t)l * kNH;
    const float* onwl = onorm_w + (size_t)l * kI;
    const float* skwl = skip_w + (size_t)l * kI;
    const float* dbl  = down_b + (size_t)l * kD;
    const unsigned short* upWTl = upWT + (size_t)l * 2 * kI * kD;
    const unsigned short* dnWTl = dnWT + (size_t)l * kD * kI;
    const unsigned short* gWTl  = gWT + (size_t)l * 16 * 3072;
    const float* csuml = CSUM + (size_t)l * 2 * kI;

    gemm_up_kernel<<<512, 256, 0, stream>>>(Xb, upWTl, upbl, csuml, ST1, ST2, U, 512);
    convhead_kernel<<<1024, 256, 0, stream>>>(U, cwl, cbl, wql, wkl, wvl, XCb, qb, kbuf, vb, vt);
    prep_kernel<<<192, 256, 0, stream>>>(qb, kbuf, vb, gWTl, IGp, FGp);
    mlstm_mfma_kernel<<<256, 512, 0, stream>>>(
        qb, kbuf, vt, IGp, FGp, igbl, fgbl, U, XCb, onwl, skwl, HHb);
    gemm_dn_kernel<<<256, 256, 0, stream>>>(HHb, dnWTl, dbl, X, Xb, ST1, ST2, 256);
  }

  head_kernel<<<kB * kPRED, 256, 0, stream>>>(X, post_w, head_W, head_b, out);
}

// Round 18
// 367.838 us; speedup vs baseline: 1.0357x; 1.0357x over previous
//
#include <hip/hip_runtime.h>
#include <math.h>

// ---- dims ----
static constexpr int kB = 8, kS = 512;
static constexpr int kD = 512, kI = 1024, kNH = 8, kDH = 128;
static constexpr int kL = 4, kPRED = 96, kCOUT = 7;
static constexpr int kM = kB * kS; // 4096 rows

typedef __bf16 bf16x8 __attribute__((ext_vector_type(8)));
typedef float f32x4 __attribute__((ext_vector_type(4)));

#define MFMA_BF16(a, b, c) __builtin_amdgcn_mfma_f32_16x16x32_bf16((a), (b), (c), 0, 0, 0)

typedef __attribute__((address_space(1))) const unsigned char* as1cp;
typedef __attribute__((address_space(3))) unsigned char* as3p;
__device__ __forceinline__ void gload16(const void* g, void* l) {
  __builtin_amdgcn_global_load_lds((as1cp)g, (as3p)l, 16, 0, 0);
}

__device__ __forceinline__ unsigned short f2bf(float f) {
  union { float f; unsigned u; } v; v.f = f;
  unsigned r = v.u + 0x7fffu + ((v.u >> 16) & 1u);
  return (unsigned short)(r >> 16);
}
__device__ __forceinline__ float bf2f(unsigned short h) {
  union { unsigned u; float f; } v; v.u = (unsigned)h << 16; return v.f;
}

// ================== init: embed(+stats) | up-T(gamma-folded) | dn-T | gates-T | colsum ====
// grid: [0,4096) embed; [4096,5120) upT; [5120,5632) dnT; [5632,5680) gates;
//       [5680,5936) colsum (256 blocks: 32 cols x 8 k-segments each)
__global__ __launch_bounds__(256) void init_kernel(
    const float* __restrict__ xe, const float* __restrict__ xme,
    const float* __restrict__ embW, const float* __restrict__ embb,
    const float* __restrict__ lnw_all,
    const float* __restrict__ upW, const float* __restrict__ dnW,
    const float* __restrict__ igW, const float* __restrict__ fgW,
    float* __restrict__ x, unsigned short* __restrict__ xb,
    float* __restrict__ st1, float* __restrict__ st2,
    unsigned short* __restrict__ upWT, unsigned short* __restrict__ dnWT,
    unsigned short* __restrict__ gWT, float* __restrict__ colsum) {
  __shared__ float t[64][65];
  __shared__ float f[11], a1[4], a2[4];
  __shared__ float csx[32][8];
  int id = blockIdx.x, tid = threadIdx.x;
  if (id < 4096) {
    int m = id;
    if (tid < 7) f[tid] = xe[m * 7 + tid];
    else if (tid < 11) f[tid] = xme[m * 4 + (tid - 7)];
    __syncthreads();
    float v0 = embb[tid], v1 = embb[256 + tid];
#pragma unroll
    for (int e = 0; e < 11; ++e) {
      v0 += f[e] * embW[e * kD + tid];
      v1 += f[e] * embW[e * kD + 256 + tid];
    }
    x[(size_t)m * kD + tid] = v0;
    x[(size_t)m * kD + 256 + tid] = v1;
    xb[(size_t)m * kD + tid] = f2bf(v0);
    xb[(size_t)m * kD + 256 + tid] = f2bf(v1);
    float s1 = v0 + v1, s2 = v0 * v0 + v1 * v1;
#pragma unroll
    for (int o = 1; o < 64; o <<= 1) { s1 += __shfl_xor(s1, o, 64); s2 += __shfl_xor(s2, o, 64); }
    if ((tid & 63) == 0) { a1[tid >> 6] = s1; a2[tid >> 6] = s2; }
    __syncthreads();
    if (tid == 0) {
      st1[m] = a1[0] + a1[1] + a1[2] + a1[3];
      st2[m] = a2[0] + a2[1] + a2[2] + a2[3];
    } else if (tid < 4) {
      st1[tid * 4096 + m] = 0.f;
      st2[tid * 4096 + m] = 0.f;
    }
  } else if (id < 5120) {
    int tt = id - 4096;
    int l = tt >> 8, rem = tt & 255;
    int n0 = (rem >> 3) * 64, k0 = (rem & 7) * 64;
    const float* Wl = upW + (size_t)l * 2048 * 512;
    const float* lnw = lnw_all + (size_t)l * kD;
    unsigned short* WTl = upWT + (size_t)l * 2048 * 512;
    for (int idx = tid; idx < 4096; idx += 256) {
      int r = idx >> 6, c = idx & 63;
      t[r][c] = Wl[(size_t)(k0 + r) * 2048 + n0 + c];
    }
    __syncthreads();
    for (int idx = tid; idx < 4096; idx += 256) {
      int r = idx >> 6, c = idx & 63;
      WTl[(size_t)(n0 + r) * 512 + k0 + c] = f2bf(lnw[k0 + c] * t[c][r]);
    }
  } else if (id < 5632) {
    int tt = id - 5120;
    int l = tt >> 7, rem = tt & 127;
    int n0 = (rem >> 4) * 64, k0 = (rem & 15) * 64;
    const float* Wl = dnW + (size_t)l * 512 * 1024;
    unsigned short* WTl = dnWT + (size_t)l * 512 * 1024;
    for (int idx = tid; idx < 4096; idx += 256) {
      int r = idx >> 6, c = idx & 63;
      t[r][c] = Wl[(size_t)(k0 + r) * 512 + n0 + c];
    }
    __syncthreads();
    for (int idx = tid; idx < 4096; idx += 256) {
      int r = idx >> 6, c = idx & 63;
      WTl[(size_t)(n0 + r) * 1024 + k0 + c] = f2bf(t[c][r]);
    }
  } else if (id < 5680) {
    int tt = id - 5632;
    int l = tt / 12, kc = tt % 12;
    int k = kc * 256 + tid;
    const float* igl = igW + (size_t)l * 3072 * 8;
    const float* fgl = fgW + (size_t)l * 3072 * 8;
    unsigned short* gl = gWT + (size_t)l * 16 * 3072;
#pragma unroll
    for (int h = 0; h < 8; ++h) {
      gl[(size_t)h * 3072 + k] = f2bf(igl[(size_t)k * 8 + h]);
      gl[(size_t)(8 + h) * 3072 + k] = f2bf(fgl[(size_t)k * 8 + h]);
    }
  } else {
    // colsum: 256 blocks; block handles 32 cols x 8 k-segments (64 k each)
    int tt = id - 5680;
    int l = tt >> 6, n0 = (tt & 63) * 32;
    int c = tid >> 3, seg = tid & 7;
    int col = n0 + c;
    const float* Wl = upW + (size_t)l * 2048 * 512;
    const float* lnw = lnw_all + (size_t)l * kD;
    float ps = 0.f;
#pragma unroll 4
    for (int j = 0; j < 64; ++j) {
      int k = seg * 64 + j;
      ps += bf2f(f2bf(lnw[k] * Wl[(size_t)k * 2048 + col]));
    }
    csx[c][seg] = ps;
    __syncthreads();
    if (seg == 0) {
      float cs = 0.f;
#pragma unroll
      for (int j = 0; j < 8; ++j) cs += csx[c][j];
      colsum[(size_t)l * 2048 + col] = cs;
    }
  }
}

// ============== up-GEMM: U = LNfactored(X) @ upWT'^T + bias  (BM=128, NBN=16) =============
__global__ __launch_bounds__(256) void gemm_up_kernel(
    const unsigned short* __restrict__ A, const unsigned short* __restrict__ BT,
    const float* __restrict__ bias, const float* __restrict__ colsum,
    const float* __restrict__ st1, const float* __restrict__ st2,
    unsigned short* __restrict__ C, int nwg) {
  constexpr int BM = 128, NBN = 16, Kd = 512, N = 2048;
  constexpr int A_ISS = BM / 8, PER_W = (A_ISS + 16) / 4, MR = BM / 32;
  __shared__ __align__(16) char As[BM * 128];
  __shared__ __align__(16) char Bs[16384];
  int tid = threadIdx.x, w = tid >> 6, l = tid & 63;
  int lr = l & 15, lg = l >> 4;
  int id = blockIdx.x;
  int q = nwg >> 3, r = nwg & 7;
  int xcd = id & 7, pos = id >> 3;
  int wg = (xcd < r ? xcd * (q + 1) : r * (q + 1) + (xcd - r) * q) + pos;
  int bn = wg % NBN, bm = wg / NBN;
  int wrow = (w >> 1) * (BM / 2), wcol = (w & 1) * 64;
  f32x4 acc[MR][4] = {};
  for (int kt = 0; kt < Kd; kt += 64) {
    __syncthreads();
#pragma unroll
    for (int j = 0; j < PER_W; ++j) {
      int g = w * PER_W + j;
      bool isA = g < A_ISS;
      int ii = isA ? g : g - A_ISS;
      int row = ii * 8 + (l >> 3);
      int chunk = (l & 7) ^ (row & 7);
      const unsigned short* src = isA
          ? A + ((size_t)(bm * BM + row) * Kd + kt) + chunk * 8
          : BT + ((size_t)(bn * 128 + row) * Kd + kt) + chunk * 8;
      char* dst = (isA ? As : Bs) + ii * 1024;
      gload16(src, dst);
    }
    __syncthreads();
#pragma unroll
    for (int kk = 0; kk < 2; ++kk) {
      bf16x8 af[MR], bfr[4];
#pragma unroll
      for (int m = 0; m < MR; ++m) {
        int row = wrow + m * 16 + lr;
        int ch = (kk * 4 + lg) ^ (row & 7);
        af[m] = *(const bf16x8*)(As + row * 128 + ch * 16);
      }
#pragma unroll
      for (int n = 0; n < 4; ++n) {
        int row = wcol + n * 16 + lr;
        int ch = (kk * 4 + lg) ^ (row & 7);
        bfr[n] = *(const bf16x8*)(Bs + row * 128 + ch * 16);
      }
#pragma unroll
      for (int m = 0; m < MR; ++m)
#pragma unroll
        for (int n = 0; n < 4; ++n)
          acc[m][n] = MFMA_BF16(af[m], bfr[n], acc[m][n]);
    }
  }
  float mu_r[MR][4], rs_r[MR][4];
#pragma unroll
  for (int m = 0; m < MR; ++m)
#pragma unroll
    for (int i = 0; i < 4; ++i) {
      int row = bm * BM + wrow + m * 16 + lg * 4 + i;
      float s1 = st1[row] + st1[4096 + row] + st1[8192 + row] + st1[12288 + row];
      float s2 = st2[row] + st2[4096 + row] + st2[8192 + row] + st2[12288 + row];
      float mu = s1 * (1.f / 512.f);
      float var = s2 * (1.f / 512.f) - mu * mu;
      mu_r[m][i] = mu;
      rs_r[m][i] = rsqrtf(var + 1e-5f);
    }
#pragma unroll
  for (int n = 0; n < 4; ++n) {
    int col = bn * 128 + wcol + n * 16 + lr;
    float bv = bias[col];
    float cs = colsum[col];
#pragma unroll
    for (int m = 0; m < MR; ++m)
#pragma unroll
      for (int i = 0; i < 4; ++i) {
        int row = bm * BM + wrow + m * 16 + lg * 4 + i;
        float v = rs_r[m][i] * (acc[m][n][i] - mu_r[m][i] * cs) + bv;
        C[(size_t)row * N + col] = f2bf(v);
      }
  }
}

// ============== dn-GEMM: X += HHb @ dnWT^T + bias; emits Xb bf16 + row-stats partials ======
__global__ __launch_bounds__(256) void gemm_dn_kernel(
    const unsigned short* __restrict__ A, const unsigned short* __restrict__ BT,
    const float* __restrict__ bias, float* __restrict__ X,
    unsigned short* __restrict__ Xb, float* __restrict__ st1, float* __restrict__ st2,
    int nwg) {
  constexpr int BM = 64, NBN = 4, Kd = 1024, N = 512;
  constexpr int A_ISS = BM / 8, PER_W = (A_ISS + 16) / 4, MR = BM / 32;
  __shared__ __align__(16) char As[BM * 128];
  __shared__ __align__(16) char Bs[16384];
  __shared__ float sst[4][32][2];
  int tid = threadIdx.x, w = tid >> 6, l = tid & 63;
  int lr = l & 15, lg = l >> 4;
  int id = blockIdx.x;
  int q = nwg >> 3, r = nwg & 7;
  int xcd = id & 7, pos = id >> 3;
  int wg = (xcd < r ? xcd * (q + 1) : r * (q + 1) + (xcd - r) * q) + pos;
  int bn = wg % NBN, bm = wg / NBN;
  int wrow = (w >> 1) * (BM / 2), wcol = (w & 1) * 64;
  f32x4 acc[MR][4] = {};
  for (int kt = 0; kt < Kd; kt += 64) {
    __syncthreads();
#pragma unroll
    for (int j = 0; j < PER_W; ++j) {
      int g = w * PER_W + j;
      bool isA = g < A_ISS;
      int ii = isA ? g : g - A_ISS;
      int row = ii * 8 + (l >> 3);
      int chunk = (l & 7) ^ (row & 7);
      const unsigned short* src = isA
          ? A + ((size_t)(bm * BM + row) * Kd + kt) + chunk * 8
          : BT + ((size_t)(bn * 128 + row) * Kd + kt) + chunk * 8;
      char* dst = (isA ? As : Bs) + ii * 1024;
      gload16(src, dst);
    }
    __syncthreads();
#pragma unroll
    for (int kk = 0; kk < 2; ++kk) {
      bf16x8 af[MR], bfr[4];
#pragma unroll
      for (int m = 0; m < MR; ++m) {
        int row = wrow + m * 16 + lr;
        int ch = (kk * 4 + lg) ^ (row & 7);
        af[m] = *(const bf16x8*)(As + row * 128 + ch * 16);
      }
#pragma unroll
      for (int n = 0; n < 4; ++n) {
        int row = wcol + n * 16 + lr;
        int ch = (kk * 4 + lg) ^ (row & 7);
        bfr[n] = *(const bf16x8*)(Bs + row * 128 + ch * 16);
      }
#pragma unroll
      for (int m = 0; m < MR; ++m)
#pragma unroll
        for (int n = 0; n < 4; ++n)
          acc[m][n] = MFMA_BF16(af[m], bfr[n], acc[m][n]);
    }
  }
  float ps1[MR][4] = {}, ps2[MR][4] = {};
#pragma unroll
  for (int n = 0; n < 4; ++n) {
    int col = bn * 128 + wcol + n * 16 + lr;
    float bv = bias[col];
#pragma unroll
    for (int m = 0; m < MR; ++m)
#pragma unroll
      for (int i = 0; i < 4; ++i) {
        int row = bm * BM + wrow + m * 16 + lg * 4 + i;
        float v = acc[m][n][i] + bv + X[(size_t)row * N + col];
        X[(size_t)row * N + col] = v;
        Xb[(size_t)row * N + col] = f2bf(v);
        ps1[m][i] += v;
        ps2[m][i] += v * v;
      }
  }
#pragma unroll
  for (int m = 0; m < MR; ++m)
#pragma unroll
    for (int i = 0; i < 4; ++i) {
#pragma unroll
      for (int off = 1; off < 16; off <<= 1) {
        ps1[m][i] += __shfl_xor(ps1[m][i], off, 16);
        ps2[m][i] += __shfl_xor(ps2[m][i], off, 16);
      }
    }
  if (lr == 0) {
#pragma unroll
    for (int m = 0; m < MR; ++m)
#pragma unroll
      for (int i = 0; i < 4; ++i) {
        int lrow = m * 16 + lg * 4 + i;  // 0..31 within wave's row set
        sst[w][lrow][0] = ps1[m][i];
        sst[w][lrow][1] = ps2[m][i];
      }
  }
  __syncthreads();
  if (tid < 64) {
    int lrow = tid & 31, half = tid >> 5;
    int wA = half * 2, wB = half * 2 + 1;
    float s1 = sst[wA][lrow][0] + sst[wB][lrow][0];
    float s2 = sst[wA][lrow][1] + sst[wB][lrow][1];
    int grow = bm * BM + half * 32 + lrow;
    st1[(size_t)bn * 4096 + grow] = s1;
    st2[(size_t)bn * 4096 + grow] = s2;
  }
}

// ==== fused causal conv(K=4)+silu + headwise q,k,v; 4 consecutive s per block ====
__global__ __launch_bounds__(256) void convhead_kernel(
    const unsigned short* __restrict__ u, const float* __restrict__ cw,
    const float* __restrict__ cb,
    const float* __restrict__ Wq, const float* __restrict__ Wk, const float* __restrict__ Wv,
    unsigned short* __restrict__ xcb, unsigned short* __restrict__ qb,
    unsigned short* __restrict__ kb, unsigned short* __restrict__ vb) {
  int id = blockIdx.x;
  int unit = (id & 7) * 128 + (id >> 3);  // bijective for 1024 blocks
  int b = unit >> 7, sq = (unit & 127) * 4;
  int n = threadIdx.x;  // channels n*4 .. n*4+3
  float xm[7][4];
#pragma unroll
  for (int j = 0; j < 7; ++j) {
    int sp = sq - 3 + j;
    if (sp >= 0) {
      unsigned long long raw = *(const unsigned long long*)&u[((size_t)(b * kS + sp)) * (2 * kI) + n * 4];
#pragma unroll
      for (int i = 0; i < 4; ++i) xm[j][i] = bf2f((unsigned short)(raw >> (i * 16)));
    } else {
#pragma unroll
      for (int i = 0; i < 4; ++i) xm[j][i] = 0.f;
    }
  }
  float4 cb4 = *(const float4*)&cb[n * 4];
  const float* cbp = &cb4.x;
  float cwv[4][4];
#pragma unroll
  for (int i = 0; i < 4; ++i) *(float4*)cwv[i] = *(const float4*)&cw[(n * 4 + i) * 4];
  float wqv[16], wkv[16], wvv[16];
#pragma unroll
  for (int o2 = 0; o2 < 4; ++o2) {
    *(float4*)&wqv[o2 * 4] = *(const float4*)&Wq[n * 16 + o2 * 4];
    *(float4*)&wkv[o2 * 4] = *(const float4*)&Wk[n * 16 + o2 * 4];
    *(float4*)&wvv[o2 * 4] = *(const float4*)&Wv[n * 16 + o2 * 4];
  }
#pragma unroll
  for (int t = 0; t < 4; ++t) {
    int s = sq + t;
    float xc[4];
    unsigned long long xcv = 0;
#pragma unroll
    for (int i = 0; i < 4; ++i) {
      float acc = cbp[i] + xm[t][i] * cwv[i][0] + xm[t + 1][i] * cwv[i][1] +
                  xm[t + 2][i] * cwv[i][2] + xm[t + 3][i] * cwv[i][3];
      xc[i] = acc / (1.f + __expf(-acc));
      xcv |= (unsigned long long)f2bf(xc[i]) << (i * 16);
    }
    *(unsigned long long*)&xcb[((size_t)(b * kS + s)) * kI + n * 4] = xcv;
    unsigned long long qv = 0, kv = 0, vv = 0;
#pragma unroll
    for (int o = 0; o < 4; ++o) {
      float aq = 0, ak = 0, av = 0;
#pragma unroll
      for (int i = 0; i < 4; ++i) {
        aq += xc[i] * wqv[o * 4 + i];
        ak += xc[i] * wkv[o * 4 + i];
        av += xm[t + 3][i] * wvv[o * 4 + i];
      }
      qv |= (unsigned long long)f2bf(aq) << (o * 16);
      kv |= (unsigned long long)f2bf(ak) << (o * 16);
      vv |= (unsigned long long)f2bf(av) << (o * 16);
    }
    size_t base = ((size_t)(b * 8 + (n >> 5)) * kS + s) * kDH + (n & 31) * 4;
    *(unsigned long long*)&qb[base] = qv;
    *(unsigned long long*)&kb[base] = kv;
    *(unsigned long long*)&vb[base] = vv;
  }
}

// ============ merged prep: gates MFMA (blocks 0..191) + V transpose (blocks 192..703) ====
__global__ __launch_bounds__(256) void prep_kernel(
    const unsigned short* __restrict__ qb, const unsigned short* __restrict__ kb,
    const unsigned short* __restrict__ vb, const unsigned short* __restrict__ gWT,
    float* __restrict__ IGp, float* __restrict__ FGp, unsigned short* __restrict__ vt) {
  __shared__ __align__(16) char smem[16640];
  int id = blockIdx.x;
  int tid = threadIdx.x;
  if (id < 192) {
    int src = id >> 6;
    int blk = id & 63;
    int b = blk >> 3, s0 = (blk & 7) * 64;
    int w = tid >> 6, l = tid & 63;
    int lr = l & 15, lg = l >> 4;
    char* Ts = smem;
    const unsigned short* srcb = (src == 0) ? qb : (src == 1) ? kb : vb;
    f32x4 acc = {};
    for (int kc8 = 0; kc8 < 8; ++kc8) {
      const unsigned short* srcbase = srcb + ((size_t)(b * 8 + kc8) * kS + s0) * kDH;
      __syncthreads();
#pragma unroll
      for (int j = 0; j < 4; ++j) {
        int issue = w * 4 + j;
        int row = issue * 4 + (l >> 4);
        int chunk = (l & 15) ^ (row & 7);
        gload16(srcbase + row * 128 + chunk * 8, Ts + issue * 1024);
      }
      __syncthreads();
#pragma unroll
      for (int kk = 0; kk < 4; ++kk) {
        int arow = w * 16 + lr;
        int ch = (kk * 4 + lg) ^ (arow & 7);
        bf16x8 af = *(const bf16x8*)(Ts + arow * 256 + ch * 16);
        bf16x8 bfv = *(const bf16x8*)(gWT + (size_t)lr * 3072 + (src * 8 + kc8) * 128 + kk * 32 + lg * 8);
        acc = MFMA_BF16(af, bfv, acc);
      }
    }
    float* IGo = IGp + (size_t)src * 64 * kS;
    float* FGo = FGp + (size_t)src * 64 * kS;
#pragma unroll
    for (int i = 0; i < 4; ++i) {
      int s = s0 + w * 16 + lg * 4 + i;
      if (lr < 8) IGo[((size_t)(b * 8) + lr) * kS + s] = acc[i];
      else FGo[((size_t)(b * 8) + lr - 8) * kS + s] = acc[i];
    }
  } else {
    int t = id - 192;
    int bh = t >> 3, s0 = (t & 7) * 64;
    unsigned short (*tt)[130] = (unsigned short(*)[130])smem;
    for (int idx = tid; idx < 64 * 128; idx += 256) {
      int sl = idx >> 7, d = idx & 127;
      tt[sl][d] = vb[((size_t)bh * kS + s0 + sl) * kDH + d];
    }
    __syncthreads();
    for (int idx = tid; idx < 64 * 128; idx += 256) {
      int dl = idx >> 6, sl = idx & 63;
      vt[((size_t)bh * kDH + dl) * kS + s0 + sl] = tt[sl][dl];
    }
  }
}

// ======================= mLSTM parallel via MFMA, fused scan + mh_norm/skip/gate ==========
__global__ __launch_bounds__(512) void mlstm_mfma_kernel(
    const unsigned short* __restrict__ qb, const unsigned short* __restrict__ kb,
    const unsigned short* __restrict__ vt,
    const float* __restrict__ IGp, const float* __restrict__ FGp,
    const float* __restrict__ igb, const float* __restrict__ fgb,
    const unsigned short* __restrict__ u, const unsigned short* __restrict__ xcb,
    const float* __restrict__ onw, const float* __restrict__ skw,
    unsigned short* __restrict__ hhb) {
  int id = blockIdx.x;
  int bh = (id & 7) * 8 + ((id >> 3) & 7);  // each XCD sees only 8 heads
  int pr = id >> 6;                          // 0..3
  int rtA = 7 - pr, rtB = pr;
  int b = bh >> 3, nh = bh & 7;
  int tid = threadIdx.x, w = tid >> 6, l = tid & 63;
  int g = w >> 2, wl = w & 3;
  int rt = (g == 0) ? rtA : rtB;
  int lr = l & 15, lg = l >> 4;
  __shared__ __align__(16) char Ks[2][16384];  // [64 s][128 d] bf16, RB=256
  __shared__ __align__(16) char Vs[2][16384];  // [128 d][64 s] bf16, RB=128
  __shared__ __align__(16) char Ps[8][2048];   // per-wave [16][64] bf16, RB=128
  __shared__ float avs[512], incs[512], pms[512];
  __shared__ float wsum[8], wmax[8];

  const unsigned short* kbh = kb + (size_t)bh * kS * kDH;
  const unsigned short* vbh = vt + (size_t)bh * kDH * kS;

  // prologue: stage tile 0 into buffer 0 (all 8 waves: 2 K-issues + 2 V-issues each)
#pragma unroll
  for (int j = 0; j < 2; ++j) {
    int issue = w * 2 + j;
    int row = issue * 4 + (l >> 4);
    int chunk = (l & 15) ^ (row & 7);
    gload16(kbh + row * 128 + chunk * 8, Ks[0] + issue * 1024);
  }
#pragma unroll
  for (int j = 0; j < 2; ++j) {
    int vi = w * 2 + j;
    int row = vi * 8 + (l >> 3);
    int chunk = (l & 7) ^ (row & 7);
    gload16(vbh + (size_t)row * kS + chunk * 8, Vs[0] + vi * 1024);
  }

  // ---- in-block scan for this head (hidden under tile-0 DMA) ----
  {
    int lane = tid & 63, wid2 = tid >> 6;
    const size_t ss = (size_t)64 * kS;
    size_t o = (size_t)bh * kS + tid;
    float igv = IGp[o] + IGp[ss + o] + IGp[2 * ss + o] + igb[nh];
    float fgv = FGp[o] + FGp[ss + o] + FGp[2 * ss + o] + fgb[nh];
    float lf = fminf(fgv, 0.f) - log1pf(__expf(-fabsf(fgv)));
    float x = lf;
#pragma unroll
    for (int off = 1; off < 64; off <<= 1) {
      float v = __shfl_up(x, off, 64);
      if (lane >= off) x += v;
    }
    if (lane == 63) wsum[wid2] = x;
    __syncthreads();
    float base = 0.f;
    for (int i2 = 0; i2 < wid2; ++i2) base += wsum[i2];
    float inct = x + base;
    incs[tid] = inct;
    float av = igv - inct;
    avs[tid] = 0.08838834764831845f * __expf(av);
    float y = av;
#pragma unroll
    for (int off = 1; off < 64; off <<= 1) {
      float v = __shfl_up(y, off, 64);
      if (lane >= off) y = fmaxf(y, v);
    }
    if (lane == 63) wmax[wid2] = y;
    __syncthreads();
    float mb2 = y;
    for (int i2 = 0; i2 < wid2; ++i2) mb2 = fmaxf(mb2, wmax[i2]);
    pms[tid] = mb2;
  }

  bf16x8 qf[4];
  int qrow = rt * 64 + wl * 16 + lr;
  const unsigned short* qrp = qb + ((size_t)bh * kS + qrow) * kDH + lg * 8;
#pragma unroll
  for (int kk = 0; kk < 4; ++kk) qf[kk] = *(const bf16x8*)(qrp + kk * 32);

  __syncthreads();  // scan results + tile-0 staging visible

  float pm_r[4], epm[4];
#pragma unroll
  for (int i = 0; i < 4; ++i) {
    pm_r[i] = pms[rt * 64 + wl * 16 + lg * 4 + i];
    epm[i] = __expf(-pm_r[i]);
  }

  f32x4 oacc[8] = {};
  float rsum[4] = {};

  int cur = 0;
#pragma unroll 1
  for (int ct = 0; ct <= rtA; ++ct) {
    if (ct < rtA) {
      const unsigned short* kbase = kbh + (size_t)(ct + 1) * 64 * kDH;
      const unsigned short* vbase = vbh + (size_t)(ct + 1) * 64;
#pragma unroll
      for (int j = 0; j < 2; ++j) {
        int issue = w * 2 + j;
        int row = issue * 4 + (l >> 4);
        int chunk = (l & 15) ^ (row & 7);
        gload16(kbase + row * 128 + chunk * 8, Ks[cur ^ 1] + issue * 1024);
      }
#pragma unroll
      for (int j = 0; j < 2; ++j) {
        int vi = w * 2 + j;
        int row = vi * 8 + (l >> 3);
        int chunk = (l & 7) ^ (row & 7);
        gload16(vbase + (size_t)row * kS + chunk * 8, Vs[cur ^ 1] + vi * 1024);
      }
    }
    if (ct <= rt) {
      // QK^T
      f32x4 sacc[4] = {};
      __builtin_amdgcn_s_setprio(1);
#pragma unroll
      for (int n = 0; n < 4; ++n) {
#pragma unroll
        for (int kk = 0; kk < 4; ++kk) {
          int krow = n * 16 + lr;
          int ch = (kk * 4 + lg) ^ (krow & 7);
          bf16x8 kf = *(const bf16x8*)(Ks[cur] + krow * 256 + ch * 16);
          sacc[n] = MFMA_BF16(qf[kk], kf, sacc[n]);
        }
      }
      __builtin_amdgcn_s_setprio(0);
      // transform scores -> P (bf16 in per-wave LDS), accumulate row sums.
      // Mask peel: cndmask chain only on the diagonal tile (ct == rt).
      if (ct < rt) {
#pragma unroll
        for (int n = 0; n < 4; ++n) {
          float eav = avs[ct * 64 + n * 16 + lr];
#pragma unroll
          for (int i = 0; i < 4; ++i) {
            float s = sacc[n][i] * (eav * epm[i]);
            rsum[i] += s;
            int prow = lg * 4 + i, pcol = n * 16 + lr;
            int byte = prow * 128 + ((((pcol >> 3) ^ (prow & 7))) << 4) + (pcol & 7) * 2;
            *(unsigned short*)(Ps[w] + byte) = f2bf(s);
          }
        }
      } else {
#pragma unroll
        for (int n = 0; n < 4; ++n) {
          float eav = avs[ct * 64 + n * 16 + lr];
          int cg = ct * 64 + n * 16 + lr;
#pragma unroll
          for (int i = 0; i < 4; ++i) {
            int rg = rt * 64 + wl * 16 + lg * 4 + i;
            float s = (cg <= rg) ? sacc[n][i] * (eav * epm[i]) : 0.f;
            rsum[i] += s;
            int prow = lg * 4 + i, pcol = n * 16 + lr;
            int byte = prow * 128 + ((((pcol >> 3) ^ (prow & 7))) << 4) + (pcol & 7) * 2;
            *(unsigned short*)(Ps[w] + byte) = f2bf(s);
          }
        }
      }
      // PV
      __builtin_amdgcn_s_setprio(1);
#pragma unroll
      for (int kk = 0; kk < 2; ++kk) {
        int prow = lr;
        int pch = (kk * 4 + lg) ^ (prow & 7);
        bf16x8 pf = *(const bf16x8*)(Ps[w] + prow * 128 + pch * 16);
#pragma unroll
        for (int nb = 0; nb < 8; ++nb) {
          int vrow = nb * 16 + lr;
          int vch = (kk * 4 + lg) ^ (vrow & 7);
          bf16x8 vf = *(const bf16x8*)(Vs[cur] + vrow * 128 + vch * 16);
          oacc[nb] = MFMA_BF16(pf, vf, oacc[nb]);
        }
      }
      __builtin_amdgcn_s_setprio(0);
    }
    __syncthreads();  // drains staging DMA + protects buffer swap
    cur ^= 1;
  }

#pragma unroll
  for (int i = 0; i < 4; ++i)
#pragma unroll
    for (int off = 1; off < 16; off <<= 1) rsum[i] += __shfl_xor(rsum[i], off, 16);
  float ninv[4];
#pragma unroll
  for (int i = 0; i < 4; ++i) {
    int rg = rt * 64 + wl * 16 + lg * 4 + i;
    float e0 = __expf(-incs[rg] - pm_r[i]);
    float nn = fmaxf(fabsf(rsum[i]), e0);
    ninv[i] = 1.f / (nn + 1e-6f);
  }
  // ---- fused mh_norm (LN over DH=128 within 16-lane groups) + skip + output gate ----
  float val[8][4];
  float s1[4] = {}, s2[4] = {};
#pragma unroll
  for (int nb = 0; nb < 8; ++nb)
#pragma unroll
    for (int i = 0; i < 4; ++i) {
      float v = oacc[nb][i] * ninv[i];
      val[nb][i] = v;
      s1[i] += v; s2[i] += v * v;
    }
#pragma unroll
  for (int i = 0; i < 4; ++i) {
#pragma unroll
    for (int off = 1; off < 16; off <<= 1) {
      s1[i] += __shfl_xor(s1[i], off, 16);
      s2[i] += __shfl_xor(s2[i], off, 16);
    }
  }
#pragma unroll
  for (int i = 0; i < 4; ++i) {
    int rg = rt * 64 + wl * 16 + lg * 4 + i;
    float mu = s1[i] * (1.f / 128.f);
    float var = s2[i] * (1.f / 128.f) - mu * mu;
    float rstd = rsqrtf(var + 1e-5f);
    size_t rowbase = (size_t)(b * kS + rg);
    const unsigned short* uz = u + rowbase * (2 * kI) + kI + nh * kDH;
    const unsigned short* xz = xcb + rowbase * kI + nh * kDH;
    unsigned short* hz = hhb + rowbase * kI + nh * kDH;
#pragma unroll
    for (int nb = 0; nb < 8; ++nb) {
      int c = nh * kDH + nb * 16 + lr;
      int cc = nb * 16 + lr;
      float nv = (val[nb][i] - mu) * rstd * onw[c];
      float z = bf2f(uz[cc]);
      float sz = z / (1.f + __expf(-z));
      float xcv = bf2f(xz[cc]);
      hz[cc] = f2bf((nv + skw[c] * xcv) * sz);
    }
  }
}

// ======================= post-norm + head projection (last 96 rows/batch) =======================
__global__ __launch_bounds__(256) void head_kernel(
    const float* __restrict__ x, const float* __restrict__ pw,
    const float* __restrict__ hW, const float* __restrict__ hb, float* __restrict__ out) {
  int row = blockIdx.x;  // 0..767
  int b = row / kPRED, p = row % kPRED;
  int m = b * kS + (kS - kPRED) + p;
  int tid = threadIdx.x;
  float v0 = x[(size_t)m * kD + tid];
  float v1 = x[(size_t)m * kD + 256 + tid];
  float s1 = v0 + v1, s2 = v0 * v0 + v1 * v1;
#pragma unroll
  for (int o = 1; o < 64; o <<= 1) { s1 += __shfl_xor(s1, o, 64); s2 += __shfl_xor(s2, o, 64); }
  __shared__ float a1[4], a2[4];
  if ((tid & 63) == 0) { a1[tid >> 6] = s1; a2[tid >> 6] = s2; }
  __syncthreads();
  float t1 = a1[0] + a1[1] + a1[2] + a1[3];
  float t2 = a2[0] + a2[1] + a2[2] + a2[3];
  float mu = t1 * (1.f / kD);
  float var = t2 * (1.f / kD) - mu * mu;
  float rs = rsqrtf(var + 1e-5f);
  __shared__ float buf[512];
  buf[tid] = (v0 - mu) * rs * pw[tid];
  buf[256 + tid] = (v1 - mu) * rs * pw[256 + tid];
  __syncthreads();
  float acc[7] = {};
  for (int kk = tid; kk < 512; kk += 256) {
    float g = buf[kk];
#pragma unroll
    for (int n = 0; n < 7; ++n) acc[n] += g * hW[kk * 7 + n];
  }
  __shared__ float red[256 * 9];
#pragma unroll
  for (int n = 0; n < 7; ++n) red[tid * 9 + n] = acc[n];
  __syncthreads();
  for (int off = 128; off >= 1; off >>= 1) {
    if (tid < off) {
#pragma unroll
      for (int n = 0; n < 7; ++n) red[tid * 9 + n] += red[(tid + off) * 9 + n];
    }
    __syncthreads();
  }
  if (tid < 7) out[(size_t)row * 7 + tid] = red[tid] + hb[tid];
}

// ======================= host launch =======================
extern "C" void kernel_launch(void* const* d_in, const int* in_sizes, int n_in,
                              void* d_out, int out_size, void* d_ws, size_t ws_size,
                              hipStream_t stream) {
  const float* x_enc    = (const float*)d_in[0];
  const float* x_mark   = (const float*)d_in[1];
  const float* emb_W    = (const float*)d_in[4];
  const float* emb_b    = (const float*)d_in[5];
  const float* blk_ln_w = (const float*)d_in[6];
  const float* up_W     = (const float*)d_in[7];
  const float* up_b     = (const float*)d_in[8];
  const float* conv_w   = (const float*)d_in[9];
  const float* conv_b   = (const float*)d_in[10];
  const float* Wq       = (const float*)d_in[11];
  const float* Wk       = (const float*)d_in[12];
  const float* Wv       = (const float*)d_in[13];
  const float* ig_W     = (const float*)d_in[14];
  const float* ig_b     = (const float*)d_in[15];
  const float* fg_W     = (const float*)d_in[16];
  const float* fg_b     = (const float*)d_in[17];
  const float* onorm_w  = (const float*)d_in[18];
  const float* skip_w   = (const float*)d_in[19];
  const float* down_W   = (const float*)d_in[20];
  const float* down_b   = (const float*)d_in[21];
  const float* post_w   = (const float*)d_in[22];
  const float* head_W   = (const float*)d_in[23];
  const float* head_b   = (const float*)d_in[24];
  float* out = (float*)d_out;

  char* ws = (char*)d_ws;
  float* X  = (float*)ws;                     ws += (size_t)kM * kD * 4;
  unsigned short* Xb   = (unsigned short*)ws; ws += (size_t)kM * kD * 2;
  unsigned short* U    = (unsigned short*)ws; ws += (size_t)kM * 2 * kI * 2;
  unsigned short* XCb  = (unsigned short*)ws; ws += (size_t)kM * kI * 2;
  unsigned short* HHb  = (unsigned short*)ws; ws += (size_t)kM * kI * 2;
  unsigned short* qb   = (unsigned short*)ws; ws += (size_t)kM * kI * 2;
  unsigned short* kbuf = (unsigned short*)ws; ws += (size_t)kM * kI * 2;
  unsigned short* vb   = (unsigned short*)ws; ws += (size_t)kM * kI * 2;
  unsigned short* vt   = (unsigned short*)ws; ws += (size_t)kM * kI * 2;
  unsigned short* upWT = (unsigned short*)ws; ws += (size_t)kL * 2 * kI * kD * 2;
  unsigned short* dnWT = (unsigned short*)ws; ws += (size_t)kL * kD * kI * 2;
  unsigned short* gWT  = (unsigned short*)ws; ws += (size_t)kL * 16 * 3072 * 2;
  float* IGp = (float*)ws; ws += (size_t)3 * 64 * kS * 4;
  float* FGp = (float*)ws; ws += (size_t)3 * 64 * kS * 4;
  float* ST1 = (float*)ws; ws += (size_t)4 * kM * 4;
  float* ST2 = (float*)ws; ws += (size_t)4 * kM * 4;
  float* CSUM = (float*)ws; ws += (size_t)kL * 2 * kI * 4;

  init_kernel<<<5936, 256, 0, stream>>>(
      x_enc, x_mark, emb_W, emb_b, blk_ln_w, up_W, down_W, ig_W, fg_W,
      X, Xb, ST1, ST2, upWT, dnWT, gWT, CSUM);

  for (int l = 0; l < kL; ++l) {
    const float* upbl = up_b + (size_t)l * 2 * kI;
    const float* cwl  = conv_w + (size_t)l * kI * 4;
    const float* cbl  = conv_b + (size_t)l * kI;
    const float* wql  = Wq + (size_t)l * 256 * 16;
    const float* wkl  = Wk + (size_t)l * 256 * 16;
    const float* wvl  = Wv + (size_t)l * 256 * 16;
    const float* igbl = ig_b + (size_t)l * kNH;
    const float* fgbl = fg_b + (size_t)l * kNH;
    const float* onwl = onorm_w + (size_t)l * kI;
    const float* skwl = skip_w + (size_t)l * kI;
    const float* dbl  = down_b + (size_t)l * kD;
    const unsigned short* upWTl = upWT + (size_t)l * 2 * kI * kD;
    const unsigned short* dnWTl = dnWT + (size_t)l * kD * kI;
    const unsigned short* gWTl  = gWT + (size_t)l * 16 * 3072;
    const float* csuml = CSUM + (size_t)l * 2 * kI;

    gemm_up_kernel<<<512, 256, 0, stream>>>(Xb, upWTl, upbl, csuml, ST1, ST2, U, 512);
    convhead_kernel<<<1024, 256, 0, stream>>>(U, cwl, cbl, wql, wkl, wvl, XCb, qb, kbuf, vb);
    prep_kernel<<<704, 256, 0, stream>>>(qb, kbuf, vb, gWTl, IGp, FGp, vt);
    mlstm_mfma_kernel<<<256, 512, 0, stream>>>(
        qb, kbuf, vt, IGp, FGp, igbl, fgbl, U, XCb, onwl, skwl, HHb);
    gemm_dn_kernel<<<256, 256, 0, stream>>>(HHb, dnWTl, dbl, X, Xb, ST1, ST2, 256);
  }

  head_kernel<<<kB * kPRED, 256, 0, stream>>>(X, post_w, head_W, head_b, out);
}